// Round 6
// baseline (3629.374 us; speedup 1.0000x reference)
//
#include <hip/hip_runtime.h>

#define NPTS   4096
#define NB     8
#define M1     1024     // ceil(0.25*4096)
#define M2     820      // ceil(0.2*4096)
#define MQ     9830     // 8*1024 + 1638
#define KK     16

typedef unsigned int u32;
typedef unsigned long long u64;
typedef float f32x2 __attribute__((ext_vector_type(2)));

// DPP lexicographic combine on (khi_,klo_) u64 key. VALU pipe.
// 0x121/0x122/0x124/0x128 = row_ror 1/2/4/8, 0x142/0x143 = row_bcast15/31.
// Lane 63 ends with the wave max. (Proven bit-exact R2-R5.)
#define DPP_MAX(CTRL) do {                                                         \
    u32 olo_ = (u32)__builtin_amdgcn_update_dpp((int)klo_, (int)klo_, CTRL, 0xF, 0xF, false); \
    u32 ohi_ = (u32)__builtin_amdgcn_update_dpp((int)khi_, (int)khi_, CTRL, 0xF, 0xF, false); \
    u64 ok_ = ((u64)ohi_ << 32) | olo_;                                            \
    u64 ck_ = ((u64)khi_ << 32) | klo_;                                            \
    if (ok_ > ck_) { klo_ = olo_; khi_ = ohi_; }                                   \
} while (0)

#define DPP_MIN(CTRL) do {                                                         \
    u32 olo_ = (u32)__builtin_amdgcn_update_dpp((int)klo_, (int)klo_, CTRL, 0xF, 0xF, false); \
    u32 ohi_ = (u32)__builtin_amdgcn_update_dpp((int)khi_, (int)khi_, CTRL, 0xF, 0xF, false); \
    u64 ok_ = ((u64)ohi_ << 32) | olo_;                                            \
    u64 ck_ = ((u64)khi_ << 32) | klo_;                                            \
    if (ok_ < ck_) { klo_ = olo_; khi_ = ohi_; }                                   \
} while (0)

// ---------- FPS main: 2 waves (128 thr), 32 pts/lane ----------
// Bit-exact semantics as before: d=((dx*dx+dy*dy)+dz*dz) no-contract, min(MD,d),
// argmax tie->lowest idx via u64 key (dist<<32 | ~idx) max-reduce.
__global__ __launch_bounds__(128) void fps_kernel(const float* __restrict__ pos,
                                                  int* __restrict__ picks) {
#pragma clang fp contract(off)
    __shared__ float sx[NPTS], sy[NPTS], sz[NPTS];
    __shared__ int sp[M1];
    __shared__ float slots[2][2][8];       // [parity][wave][{klo,khi,x,y,z,pad}]
    const int b = blockIdx.x;
    const int t = threadIdx.x;
    const float* cp = pos + (size_t)b * NPTS * 3;
    for (int i = t; i < NPTS * 3; i += 128) {
        float v = cp[i];
        int p = i / 3, c = i - p * 3;
        if (c == 0) sx[p] = v;
        else if (c == 1) sy[p] = v;
        else sz[p] = v;
    }
    if (t == 0) sp[0] = 0;
    __syncthreads();

    f32x2 X[16], Y[16], Z[16], MD[16];
#pragma unroll
    for (int r = 0; r < 16; ++r) {
        int p0 = (2 * r) * 128 + t, p1 = p0 + 128;
        X[r] = f32x2{sx[p0], sx[p1]};
        Y[r] = f32x2{sy[p0], sy[p1]};
        Z[r] = f32x2{sz[p0], sz[p1]};
        MD[r] = f32x2{__builtin_inff(), __builtin_inff()};
    }
    float xl = sx[0], yl = sy[0], zl = sz[0];
    const int wave = t >> 6;

    for (int s = 1; s < M1; ++s) {
        const int par = s & 1;
        const f32x2 xl2 = f32x2{xl, xl};
        const f32x2 yl2 = f32x2{yl, yl};
        const f32x2 zl2 = f32x2{zl, zl};
        float wv[16];
        int ws[16];
#pragma unroll
        for (int r = 0; r < 16; ++r) {
            f32x2 dx = X[r] - xl2;
            f32x2 dy = Y[r] - yl2;
            f32x2 dz = Z[r] - zl2;
            f32x2 d = (dx * dx + dy * dy) + dz * dz;        // contract(off)
            f32x2 m = __builtin_elementwise_min(MD[r], d);
            MD[r] = m;
            bool c = m[1] > m[0];            // slot 2r has lower point index
            wv[r] = c ? m[1] : m[0];
            ws[r] = c ? 2 * r + 1 : 2 * r;
        }
#pragma unroll
        for (int st = 8; st >= 1; st >>= 1) {
#pragma unroll
            for (int i = 0; i < 16; ++i) {
                if (i < st) {
                    if (wv[i + st] > wv[i]) { wv[i] = wv[i + st]; ws[i] = ws[i + st]; }
                }
            }
        }
        const int ci = (ws[0] << 7) + t;     // slot*128 + t
        const float cx = sx[ci], cy = sy[ci], cz = sz[ci];
        asm volatile("" :: "v"(cx), "v"(cy), "v"(cz));   // pin loads before DPP
        u32 klo_ = ~(u32)ci;
        u32 khi_ = __float_as_uint(wv[0]);
        const u32 mylo = klo_, myhi = khi_;
        DPP_MAX(0x121); DPP_MAX(0x122); DPP_MAX(0x124); DPP_MAX(0x128);
        DPP_MAX(0x142); DPP_MAX(0x143);
        const u32 wlo = (u32)__builtin_amdgcn_readlane((int)klo_, 63);
        if (mylo == wlo) {                   // unique winner lane per wave
            float4 pay;
            pay.x = __uint_as_float(mylo); pay.y = __uint_as_float(myhi);
            pay.z = cx; pay.w = cy;
            *(float4*)&slots[par][wave][0] = pay;
            slots[par][wave][4] = cz;
        }
        __syncthreads();                     // no global ops in loop -> vmcnt free
        const float4 a0 = *(const float4*)&slots[par][0][0]; const float z0 = slots[par][0][4];
        const float4 a1 = *(const float4*)&slots[par][1][0]; const float z1 = slots[par][1][4];
        u64 k0 = ((u64)__float_as_uint(a0.y) << 32) | __float_as_uint(a0.x);
        u64 k1 = ((u64)__float_as_uint(a1.y) << 32) | __float_as_uint(a1.x);
        u64 ka = k0; xl = a0.z; yl = a0.w; zl = z0;
        if (k1 > ka) { ka = k1; xl = a1.z; yl = a1.w; zl = z1; }
        if (t == 0) sp[s] = (int)~(u32)ka;
    }
    __syncthreads();
    for (int i = t; i < M1; i += 128) picks[b * M1 + i] = sp[i];
}

// ---------- ABLATION: 4-wave structure, NO barrier / NO cross-wave exchange ----------
// Each wave tracks its own winner (wrong picks, same instruction structure).
// Measures: dist+tree+DPP+readlane+dependent sx[idx] read, zero sync cost.
// 6 internal passes so this dispatch owns the top-5 rocprof rows.
__global__ __launch_bounds__(256) void fps_ablate(const float* __restrict__ pos,
                                                  int* __restrict__ junk) {
#pragma clang fp contract(off)
    __shared__ float sx[NPTS], sy[NPTS], sz[NPTS];
    const int b = blockIdx.x;
    const int t = threadIdx.x;
    const float* cp = pos + (size_t)b * NPTS * 3;
    for (int i = t; i < NPTS * 3; i += 256) {
        float v = cp[i];
        int p = i / 3, c = i - p * 3;
        if (c == 0) sx[p] = v;
        else if (c == 1) sy[p] = v;
        else sz[p] = v;
    }
    __syncthreads();
    f32x2 X[8], Y[8], Z[8];
#pragma unroll
    for (int r = 0; r < 8; ++r) {
        int p0 = (2 * r) * 256 + t, p1 = p0 + 256;
        X[r] = f32x2{sx[p0], sx[p1]};
        Y[r] = f32x2{sy[p0], sy[p1]};
        Z[r] = f32x2{sz[p0], sz[p1]};
    }
    u32 acc = 0;
    float carry = 0.0f;
    for (int pass = 0; pass < 6; ++pass) {
        f32x2 MD[8];
#pragma unroll
        for (int r = 0; r < 8; ++r) MD[r] = f32x2{__builtin_inff(), __builtin_inff()};
        float xl = sx[0], yl = sy[0], zl = sz[0];
        for (int s = 1; s < M1; ++s) {
            const f32x2 xl2 = f32x2{xl, xl};
            const f32x2 yl2 = f32x2{yl, yl};
            const f32x2 zl2 = f32x2{zl, zl};
            float wv[8];
            int ws[8];
#pragma unroll
            for (int r = 0; r < 8; ++r) {
                f32x2 dx = X[r] - xl2;
                f32x2 dy = Y[r] - yl2;
                f32x2 dz = Z[r] - zl2;
                f32x2 d = (dx * dx + dy * dy) + dz * dz;
                f32x2 m = __builtin_elementwise_min(MD[r], d);
                MD[r] = m;
                bool c = m[1] > m[0];
                wv[r] = c ? m[1] : m[0];
                ws[r] = c ? 2 * r + 1 : 2 * r;
            }
#pragma unroll
            for (int st = 4; st >= 1; st >>= 1) {
#pragma unroll
                for (int i = 0; i < 8; ++i) {
                    if (i < st) {
                        if (wv[i + st] > wv[i]) { wv[i] = wv[i + st]; ws[i] = ws[i + st]; }
                    }
                }
            }
            const int ci = (ws[0] << 8) + t;
            u32 klo_ = ~(u32)ci;
            u32 khi_ = __float_as_uint(wv[0]);
            DPP_MAX(0x121); DPP_MAX(0x122); DPP_MAX(0x124); DPP_MAX(0x128);
            DPP_MAX(0x142); DPP_MAX(0x143);
            const int idx = (int)~(u32)__builtin_amdgcn_readlane((int)klo_, 63);
            xl = sx[idx]; yl = sy[idx]; zl = sz[idx];   // dependent broadcast read
            acc ^= (u32)idx;
        }
        carry += MD[0][0];                   // keep MD live across passes
    }
    junk[b * 256 + t] = (int)(acc ^ __float_as_uint(carry) ^ __float_as_uint(sx[t & (NPTS - 1)]));
}

// ---------------- build combined_idx + row ----------------
__global__ __launch_bounds__(256) void build_kernel(const int* __restrict__ picks,
                                                    int* __restrict__ out) {
    int i = blockIdx.x * 256 + threadIdx.x;
    if (i < MQ) {
        int v;
        if (i < NB * M1) {
            int b = i >> 10;
            v = b * NPTS + picks[i];
        } else {
            int e = i - NB * M1;
            int b = e / M2;
            int j = e - b * M2;
            v = b * NPTS + picks[b * M1 + j];      // extra = prefix of base FPS
        }
        out[i] = v;
    }
    if (i < MQ * KK) {
        out[MQ + i] = i >> 4;                      // row = repeat(arange(MQ), 16)
    }
}

// ---------------- kNN: one wave per query ----------------
__global__ __launch_bounds__(256) void knn_kernel(const float* __restrict__ pos,
                                                  int* __restrict__ out) {
#pragma clang fp contract(off)
    const int q = blockIdx.x * 4 + (threadIdx.x >> 6);
    const int l = threadIdx.x & 63;
    if (q >= MQ) return;
    const int cidx = out[q];
    const int qb = cidx >> 12;
    const float qx = pos[(size_t)cidx * 3 + 0];
    const float qy = pos[(size_t)cidx * 3 + 1];
    const float qz = pos[(size_t)cidx * 3 + 2];
    const float* cp = pos + (size_t)qb * NPTS * 3;
    float D[64];
    float lv = __builtin_inff(); int li = 0;
#pragma unroll
    for (int j = 0; j < 64; ++j) {
        int p = j * 64 + l;
        float dx = cp[p * 3 + 0] - qx;
        float dy = cp[p * 3 + 1] - qy;
        float dz = cp[p * 3 + 2] - qz;
        float d = dx * dx + dy * dy + dz * dz;   // contract(off)
        D[j] = d;
        if (d < lv) { lv = d; li = p; }
    }
    unsigned long long mask = 0;
    int* colout = out + MQ + MQ * KK + q * KK;
    for (int r = 0; r < KK; ++r) {
        u32 klo_ = (u32)li, khi_ = __float_as_uint(lv);
        DPP_MIN(0x121); DPP_MIN(0x122); DPP_MIN(0x124); DPP_MIN(0x128);
        DPP_MIN(0x142); DPP_MIN(0x143);
        u32 bi = (u32)__builtin_amdgcn_readlane((int)klo_, 63);
        if (l == 0) colout[r] = qb * NPTS + (int)bi;
        if ((bi & 63) == (u32)l) mask |= 1ull << (bi >> 6);
        lv = __builtin_inff(); li = 0;
#pragma unroll
        for (int j = 0; j < 64; ++j) {
            bool act = ((mask >> j) & 1ull) == 0ull;
            float d = D[j];
            if (act && d < lv) { lv = d; li = j * 64 + l; }
        }
    }
}

extern "C" void kernel_launch(void* const* d_in, const int* in_sizes, int n_in,
                              void* d_out, int out_size, void* d_ws, size_t ws_size,
                              hipStream_t stream) {
    const float* pos = (const float*)d_in[0];
    int* picks = (int*)d_ws;                 // 8*1024 int32 = 32 KB
    int* out = (int*)d_out;
    fps_kernel<<<NB, 128, 0, stream>>>(pos, picks);
    if (ws_size >= (size_t)(32 * 1024 + NB * 256 * 4)) {
        int* junk = (int*)((char*)d_ws + 32 * 1024);
        fps_ablate<<<NB, 256, 0, stream>>>(pos, junk);   // measurement only
    }
    build_kernel<<<(MQ * KK + 255) / 256, 256, 0, stream>>>(picks, out);
    knn_kernel<<<(MQ + 3) / 4, 256, 0, stream>>>(pos, out);
}

// Round 7
// 3395.174 us; speedup vs baseline: 1.0690x; 1.0690x over previous
//
#include <hip/hip_runtime.h>

#define NPTS   4096
#define NB     8
#define M1     1024     // ceil(0.25*4096)
#define M2     820      // ceil(0.2*4096)
#define MQ     9830     // 8*1024 + 1638
#define KK     16

typedef unsigned int u32;
typedef unsigned long long u64;
typedef float f32x2 __attribute__((ext_vector_type(2)));

// 5-wide DPP lexicographic-max: carries key (khi_,klo_) AND payload (x_,y_,z_).
// ctrl 0x121/0x122/0x124/0x128 = row_ror 1/2/4/8; 0x142/0x143 = row_bcast15/31.
// After all 6 levels lane 63 holds the wave winner's key+xyz. Key order proven
// bit-exact R2-R6 (dist_bits<<32 | ~idx, strict >, tie -> lowest point index).
#define DPP5_MAX(CTRL) do {                                                        \
    u32 olo_ = (u32)__builtin_amdgcn_update_dpp((int)klo_, (int)klo_, CTRL, 0xF, 0xF, false); \
    u32 ohi_ = (u32)__builtin_amdgcn_update_dpp((int)khi_, (int)khi_, CTRL, 0xF, 0xF, false); \
    u32 ox_  = (u32)__builtin_amdgcn_update_dpp((int)__float_as_uint(x_), (int)__float_as_uint(x_), CTRL, 0xF, 0xF, false); \
    u32 oy_  = (u32)__builtin_amdgcn_update_dpp((int)__float_as_uint(y_), (int)__float_as_uint(y_), CTRL, 0xF, 0xF, false); \
    u32 oz_  = (u32)__builtin_amdgcn_update_dpp((int)__float_as_uint(z_), (int)__float_as_uint(z_), CTRL, 0xF, 0xF, false); \
    u64 ok_ = ((u64)ohi_ << 32) | olo_;                                            \
    u64 ck_ = ((u64)khi_ << 32) | klo_;                                            \
    if (ok_ > ck_) { klo_ = olo_; khi_ = ohi_;                                     \
        x_ = __uint_as_float(ox_); y_ = __uint_as_float(oy_); z_ = __uint_as_float(oz_); } \
} while (0)

#define DPP_MIN(CTRL) do {                                                         \
    u32 olo_ = (u32)__builtin_amdgcn_update_dpp((int)klo_, (int)klo_, CTRL, 0xF, 0xF, false); \
    u32 ohi_ = (u32)__builtin_amdgcn_update_dpp((int)khi_, (int)khi_, CTRL, 0xF, 0xF, false); \
    u64 ok_ = ((u64)ohi_ << 32) | olo_;                                            \
    u64 ck_ = ((u64)khi_ << 32) | klo_;                                            \
    if (ok_ < ck_) { klo_ = olo_; khi_ = ohi_; }                                   \
} while (0)

// ---------------- FPS: 4 waves (256 thr) per cloud ----------------
// Bit-exact vs jax: d=((dx*dx+dy*dy)+dz*dz) f32 no-contract; min(MD,d);
// argmax tie->lowest idx. Per-step: dist+tree -> 5-wide DPP (key+xyz) ->
// lane63 unconditional publish {key,xyz} -> barrier (no global ops in loop,
// vmcnt free) -> 4-slot select w/ payload -> readfirstlane -> SGPR xl,yl,zl.
__global__ __launch_bounds__(256) void fps_kernel(const float* __restrict__ pos,
                                                  int* __restrict__ picks) {
#pragma clang fp contract(off)
    __shared__ float sx[NPTS], sy[NPTS], sz[NPTS];
    __shared__ int sp[M1];
    __shared__ __align__(64) float slots[2][4][16];  // [par][wave][{key2,pad2,xyz4,...}]
    const int b = blockIdx.x;
    const int t = threadIdx.x;
    const float* cp = pos + (size_t)b * NPTS * 3;
    for (int i = t; i < NPTS * 3; i += 256) {
        float v = cp[i];
        int p = i / 3, c = i - p * 3;
        if (c == 0) sx[p] = v;
        else if (c == 1) sy[p] = v;
        else sz[p] = v;
    }
    if (t == 0) sp[0] = 0;
    __syncthreads();

    f32x2 X[8], Y[8], Z[8], MD[8];
#pragma unroll
    for (int r = 0; r < 8; ++r) {
        int p0 = (2 * r) * 256 + t, p1 = p0 + 256;
        X[r] = f32x2{sx[p0], sx[p1]};
        Y[r] = f32x2{sy[p0], sy[p1]};
        Z[r] = f32x2{sz[p0], sz[p1]};
        MD[r] = f32x2{__builtin_inff(), __builtin_inff()};
    }
    float xl = sx[0], yl = sy[0], zl = sz[0];
    const int wave = t >> 6;

    for (int s = 1; s < M1; ++s) {
        const int par = s & 1;
        const f32x2 xl2 = f32x2{xl, xl};
        const f32x2 yl2 = f32x2{yl, yl};
        const f32x2 zl2 = f32x2{zl, zl};
        float wv[8];
        int ws[8];
#pragma unroll
        for (int r = 0; r < 8; ++r) {
            f32x2 dx = X[r] - xl2;
            f32x2 dy = Y[r] - yl2;
            f32x2 dz = Z[r] - zl2;
            f32x2 d = (dx * dx + dy * dy) + dz * dz;        // contract(off)
            f32x2 m = __builtin_elementwise_min(MD[r], d);
            MD[r] = m;
            bool c = m[1] > m[0];            // slot 2r has lower point index
            wv[r] = c ? m[1] : m[0];
            ws[r] = c ? 2 * r + 1 : 2 * r;
        }
#pragma unroll
        for (int st = 4; st >= 1; st >>= 1) {
#pragma unroll
            for (int i = 0; i < 8; ++i) {
                if (i < st) {
                    if (wv[i + st] > wv[i]) { wv[i] = wv[i + st]; ws[i] = ws[i + st]; }
                }
            }
        }
        const int ci = (ws[0] << 8) + t;
        // own-candidate xyz (2-way bank alias = free); issues before the DPP chain
        float x_ = sx[ci], y_ = sy[ci], z_ = sz[ci];
        asm volatile("" :: "v"(x_), "v"(y_), "v"(z_));
        u32 klo_ = ~(u32)ci;
        u32 khi_ = __float_as_uint(wv[0]);
        DPP5_MAX(0x121); DPP5_MAX(0x122); DPP5_MAX(0x124); DPP5_MAX(0x128);
        DPP5_MAX(0x142); DPP5_MAX(0x143);
        if ((t & 63) == 63) {                // lane 63 holds winner key+xyz
            *(u64*)&slots[par][wave][0] = ((u64)khi_ << 32) | klo_;
            float4 p4; p4.x = x_; p4.y = y_; p4.z = z_; p4.w = 0.0f;
            *(float4*)&slots[par][wave][4] = p4;
        }
        __syncthreads();                     // no global ops in loop -> vmcnt free
        const u64 k0 = *(const u64*)&slots[par][0][0];
        const u64 k1 = *(const u64*)&slots[par][1][0];
        const u64 k2 = *(const u64*)&slots[par][2][0];
        const u64 k3 = *(const u64*)&slots[par][3][0];
        const float4 p0 = *(const float4*)&slots[par][0][4];
        const float4 p1 = *(const float4*)&slots[par][1][4];
        const float4 p2 = *(const float4*)&slots[par][2][4];
        const float4 p3 = *(const float4*)&slots[par][3][4];
        u64 ka = k0; float4 pa = p0;
        if (k1 > ka) { ka = k1; pa = p1; }
        u64 kb = k2; float4 pb = p2;
        if (k3 > kb) { kb = k3; pb = p3; }
        if (kb > ka) { ka = kb; pa = pb; }
        xl = __uint_as_float((u32)__builtin_amdgcn_readfirstlane((int)__float_as_uint(pa.x)));
        yl = __uint_as_float((u32)__builtin_amdgcn_readfirstlane((int)__float_as_uint(pa.y)));
        zl = __uint_as_float((u32)__builtin_amdgcn_readfirstlane((int)__float_as_uint(pa.z)));
        if (t == 0) sp[s] = (int)~(u32)ka;
    }
    __syncthreads();
    for (int i = t; i < M1; i += 256) picks[b * M1 + i] = sp[i];
}

// ---------- ABLATION 2: dist-update + tree ONLY (no DPP / no LDS / no barrier) ----------
// xl fed back from the tree output -> preserves the true serial dependency.
// 8 passes; measures C+T per step. Results are nonsense, written to scratch.
__global__ __launch_bounds__(256) void fps_ablate2(const float* __restrict__ pos,
                                                   int* __restrict__ junk) {
#pragma clang fp contract(off)
    __shared__ float sx[NPTS], sy[NPTS], sz[NPTS];
    const int b = blockIdx.x;
    const int t = threadIdx.x;
    const float* cp = pos + (size_t)b * NPTS * 3;
    for (int i = t; i < NPTS * 3; i += 256) {
        float v = cp[i];
        int p = i / 3, c = i - p * 3;
        if (c == 0) sx[p] = v;
        else if (c == 1) sy[p] = v;
        else sz[p] = v;
    }
    __syncthreads();
    f32x2 X[8], Y[8], Z[8];
#pragma unroll
    for (int r = 0; r < 8; ++r) {
        int p0 = (2 * r) * 256 + t, p1 = p0 + 256;
        X[r] = f32x2{sx[p0], sx[p1]};
        Y[r] = f32x2{sy[p0], sy[p1]};
        Z[r] = f32x2{sz[p0], sz[p1]};
    }
    u32 acc = 0;
    float carry = 0.0f;
    for (int pass = 0; pass < 8; ++pass) {
        f32x2 MD[8];
#pragma unroll
        for (int r = 0; r < 8; ++r) MD[r] = f32x2{__builtin_inff(), __builtin_inff()};
        float xl = sx[0], yl = sy[0], zl = sz[0];
        for (int s = 1; s < M1; ++s) {
            const f32x2 xl2 = f32x2{xl, xl};
            const f32x2 yl2 = f32x2{yl, yl};
            const f32x2 zl2 = f32x2{zl, zl};
            float wv[8];
            int ws[8];
#pragma unroll
            for (int r = 0; r < 8; ++r) {
                f32x2 dx = X[r] - xl2;
                f32x2 dy = Y[r] - yl2;
                f32x2 dz = Z[r] - zl2;
                f32x2 d = (dx * dx + dy * dy) + dz * dz;
                f32x2 m = __builtin_elementwise_min(MD[r], d);
                MD[r] = m;
                bool c = m[1] > m[0];
                wv[r] = c ? m[1] : m[0];
                ws[r] = c ? 2 * r + 1 : 2 * r;
            }
#pragma unroll
            for (int st = 4; st >= 1; st >>= 1) {
#pragma unroll
                for (int i = 0; i < 8; ++i) {
                    if (i < st) {
                        if (wv[i + st] > wv[i]) { wv[i] = wv[i + st]; ws[i] = ws[i + st]; }
                    }
                }
            }
            // feed tree output back as next "pick" position: true serial dep,
            // no cross-lane / no LDS on the chain
            xl = wv[0];
            yl = 0.0f - wv[0];
            zl = wv[0] * 0.5f;
            acc ^= (u32)ws[0];
        }
        carry += MD[0][0];
    }
    junk[b * 256 + t] = (int)(acc ^ __float_as_uint(carry));
}

// ---------------- build combined_idx + row ----------------
__global__ __launch_bounds__(256) void build_kernel(const int* __restrict__ picks,
                                                    int* __restrict__ out) {
    int i = blockIdx.x * 256 + threadIdx.x;
    if (i < MQ) {
        int v;
        if (i < NB * M1) {
            int b = i >> 10;
            v = b * NPTS + picks[i];
        } else {
            int e = i - NB * M1;
            int b = e / M2;
            int j = e - b * M2;
            v = b * NPTS + picks[b * M1 + j];      // extra = prefix of base FPS
        }
        out[i] = v;
    }
    if (i < MQ * KK) {
        out[MQ + i] = i >> 4;                      // row = repeat(arange(MQ), 16)
    }
}

// ---------------- kNN: one wave per query ----------------
__global__ __launch_bounds__(256) void knn_kernel(const float* __restrict__ pos,
                                                  int* __restrict__ out) {
#pragma clang fp contract(off)
    const int q = blockIdx.x * 4 + (threadIdx.x >> 6);
    const int l = threadIdx.x & 63;
    if (q >= MQ) return;
    const int cidx = out[q];
    const int qb = cidx >> 12;
    const float qx = pos[(size_t)cidx * 3 + 0];
    const float qy = pos[(size_t)cidx * 3 + 1];
    const float qz = pos[(size_t)cidx * 3 + 2];
    const float* cp = pos + (size_t)qb * NPTS * 3;
    float D[64];
    float lv = __builtin_inff(); int li = 0;
#pragma unroll
    for (int j = 0; j < 64; ++j) {
        int p = j * 64 + l;
        float dx = cp[p * 3 + 0] - qx;
        float dy = cp[p * 3 + 1] - qy;
        float dz = cp[p * 3 + 2] - qz;
        float d = dx * dx + dy * dy + dz * dz;   // contract(off)
        D[j] = d;
        if (d < lv) { lv = d; li = p; }
    }
    unsigned long long mask = 0;
    int* colout = out + MQ + MQ * KK + q * KK;
    for (int r = 0; r < KK; ++r) {
        u32 klo_ = (u32)li, khi_ = __float_as_uint(lv);
        DPP_MIN(0x121); DPP_MIN(0x122); DPP_MIN(0x124); DPP_MIN(0x128);
        DPP_MIN(0x142); DPP_MIN(0x143);
        u32 bi = (u32)__builtin_amdgcn_readlane((int)klo_, 63);
        if (l == 0) colout[r] = qb * NPTS + (int)bi;
        if ((bi & 63) == (u32)l) mask |= 1ull << (bi >> 6);
        lv = __builtin_inff(); li = 0;
#pragma unroll
        for (int j = 0; j < 64; ++j) {
            bool act = ((mask >> j) & 1ull) == 0ull;
            float d = D[j];
            if (act && d < lv) { lv = d; li = j * 64 + l; }
        }
    }
}

extern "C" void kernel_launch(void* const* d_in, const int* in_sizes, int n_in,
                              void* d_out, int out_size, void* d_ws, size_t ws_size,
                              hipStream_t stream) {
    const float* pos = (const float*)d_in[0];
    int* picks = (int*)d_ws;                 // 8*1024 int32 = 32 KB
    int* out = (int*)d_out;
    fps_kernel<<<NB, 256, 0, stream>>>(pos, picks);
    if (ws_size >= (size_t)(32 * 1024 + NB * 256 * 4)) {
        int* junk = (int*)((char*)d_ws + 32 * 1024);
        fps_ablate2<<<NB, 256, 0, stream>>>(pos, junk);   // measurement only
    }
    build_kernel<<<(MQ * KK + 255) / 256, 256, 0, stream>>>(picks, out);
    knn_kernel<<<(MQ + 3) / 4, 256, 0, stream>>>(pos, out);
}

// Round 8
// 816.362 us; speedup vs baseline: 4.4458x; 4.1589x over previous
//
#include <hip/hip_runtime.h>

#define NPTS   4096
#define NB     8
#define M1     1024     // ceil(0.25*4096)
#define M2     820      // ceil(0.2*4096)
#define MQ     9830     // 8*1024 + 1638
#define KK     16

typedef unsigned int u32;
typedef unsigned long long u64;
typedef float f32x2 __attribute__((ext_vector_type(2)));

// Packed f32 math, forced (compiler scalarizes ext_vector f32 ops: R7 ablation
// showed ~300 instr/step vs ~140 expected). Non-volatile, pure -> schedulable.
static __device__ inline f32x2 pk_add(f32x2 a, f32x2 b) {
    f32x2 d; asm("v_pk_add_f32 %0, %1, %2" : "=v"(d) : "v"(a), "v"(b)); return d;
}
static __device__ inline f32x2 pk_mul(f32x2 a, f32x2 b) {
    f32x2 d; asm("v_pk_mul_f32 %0, %1, %2" : "=v"(d) : "v"(a), "v"(b)); return d;
}

// 2-wide DPP lexicographic combine on (khi_,klo_) u64 key. VALU pipe.
// 0x121/0x122/0x124/0x128 = row_ror 1/2/4/8; 0x142/0x143 = row_bcast15/31.
// Lane 63 ends with the wave max. Proven bit-exact R2-R7.
#define DPP_MAX(CTRL) do {                                                         \
    u32 olo_ = (u32)__builtin_amdgcn_update_dpp((int)klo_, (int)klo_, CTRL, 0xF, 0xF, false); \
    u32 ohi_ = (u32)__builtin_amdgcn_update_dpp((int)khi_, (int)khi_, CTRL, 0xF, 0xF, false); \
    u64 ok_ = ((u64)ohi_ << 32) | olo_;                                            \
    u64 ck_ = ((u64)khi_ << 32) | klo_;                                            \
    if (ok_ > ck_) { klo_ = olo_; khi_ = ohi_; }                                   \
} while (0)

#define DPP_MIN(CTRL) do {                                                         \
    u32 olo_ = (u32)__builtin_amdgcn_update_dpp((int)klo_, (int)klo_, CTRL, 0xF, 0xF, false); \
    u32 ohi_ = (u32)__builtin_amdgcn_update_dpp((int)khi_, (int)khi_, CTRL, 0xF, 0xF, false); \
    u64 ok_ = ((u64)ohi_ << 32) | olo_;                                            \
    u64 ck_ = ((u64)khi_ << 32) | klo_;                                            \
    if (ok_ < ck_) { klo_ = olo_; khi_ = ohi_; }                                   \
} while (0)

// ---------------- FPS: 4 waves (256 thr) per cloud ----------------
// Bit-exact vs jax: d = ((dx*dx+dy*dy)+dz*dz) f32, sub as add-of-negated
// (IEEE-identical), min(MD,d); argmax tie -> lowest idx via u64 key
// (dist_bits<<32 | ~idx) max-reduce. No global memory ops inside the loop
// (picks in LDS, flushed at end) -> __syncthreads vmcnt-free.
__global__ __launch_bounds__(256) void fps_kernel(const float* __restrict__ pos,
                                                  int* __restrict__ picks) {
#pragma clang fp contract(off)
    __shared__ float sx[NPTS], sy[NPTS], sz[NPTS];
    __shared__ int sp[M1];
    __shared__ __align__(16) float slots[2][4][8];  // [par][wave][{klo,khi,x,y,z,pad3}]
    const int b = blockIdx.x;
    const int t = threadIdx.x;
    const float* cp = pos + (size_t)b * NPTS * 3;
    for (int i = t; i < NPTS * 3; i += 256) {
        float v = cp[i];
        int p = i / 3, c = i - p * 3;
        if (c == 0) sx[p] = v;
        else if (c == 1) sy[p] = v;
        else sz[p] = v;
    }
    if (t == 0) sp[0] = 0;
    __syncthreads();

    f32x2 X[8], Y[8], Z[8];
    float MD0[8], MD1[8];
    int base0[8], base1[8];                 // hoisted candidate-index constants
#pragma unroll
    for (int r = 0; r < 8; ++r) {
        int p0 = (2 * r) * 256 + t, p1 = p0 + 256;
        X[r] = f32x2{sx[p0], sx[p1]};
        Y[r] = f32x2{sy[p0], sy[p1]};
        Z[r] = f32x2{sz[p0], sz[p1]};
        MD0[r] = __builtin_inff(); MD1[r] = __builtin_inff();
        base0[r] = p0; base1[r] = p1;
    }
    float xl = sx[0], yl = sy[0], zl = sz[0];
    const int wave = t >> 6;

    for (int s = 1; s < M1; ++s) {
        const int par = s & 1;
        const float xln = -xl, yln = -yl, zln = -zl;
        const f32x2 xl2n = f32x2{xln, xln};
        const f32x2 yl2n = f32x2{yln, yln};
        const f32x2 zl2n = f32x2{zln, zln};
        float mv[8];
        int mi[8];
#pragma unroll
        for (int r = 0; r < 8; ++r) {
            f32x2 dx = pk_add(X[r], xl2n);               // X - xl (exact)
            f32x2 dy = pk_add(Y[r], yl2n);
            f32x2 dz = pk_add(Z[r], zl2n);
            f32x2 d = pk_add(pk_add(pk_mul(dx, dx), pk_mul(dy, dy)), pk_mul(dz, dz));
            float m0 = __builtin_fminf(MD0[r], d[0]);    // v_min_f32
            float m1 = __builtin_fminf(MD1[r], d[1]);
            MD0[r] = m0; MD1[r] = m1;
            bool c = m1 > m0;                            // slot p0 lower index
            mv[r] = c ? m1 : m0;
            mi[r] = c ? base1[r] : base0[r];
        }
        // tree on 8 (val, idx); left always lower index -> strict > keeps
        // lowest index on ties (matches jnp.argmax)
#pragma unroll
        for (int st = 4; st >= 1; st >>= 1) {
#pragma unroll
            for (int i = 0; i < 8; ++i) {
                if (i < st) {
                    if (mv[i + st] > mv[i]) { mv[i] = mv[i + st]; mi[i] = mi[i + st]; }
                }
            }
        }
        const int ci = mi[0];
        // own-candidate xyz (2-way bank alias = free); pinned so the reads
        // issue before the DPP chain and their latency hides under it
        float cx = sx[ci], cy = sy[ci], cz = sz[ci];
        asm volatile("" :: "v"(cx), "v"(cy), "v"(cz));
        u32 klo_ = ~(u32)ci;
        u32 khi_ = __float_as_uint(mv[0]);
        const u32 mylo = klo_;
        DPP_MAX(0x121); DPP_MAX(0x122); DPP_MAX(0x124); DPP_MAX(0x128);
        DPP_MAX(0x142); DPP_MAX(0x143);
        const u32 wlo = (u32)__builtin_amdgcn_readlane((int)klo_, 63);
        const u32 whi = (u32)__builtin_amdgcn_readlane((int)khi_, 63);
        if (mylo == wlo) {                   // unique winner lane per wave
            float4 pay;
            pay.x = __uint_as_float(wlo); pay.y = __uint_as_float(whi);
            pay.z = cx; pay.w = cy;
            *(float4*)&slots[par][wave][0] = pay;
            slots[par][wave][4] = cz;
        }
        __syncthreads();                     // no global ops in loop -> vmcnt free
        const float4 a0 = *(const float4*)&slots[par][0][0]; const float z0 = slots[par][0][4];
        const float4 a1 = *(const float4*)&slots[par][1][0]; const float z1 = slots[par][1][4];
        const float4 a2 = *(const float4*)&slots[par][2][0]; const float z2 = slots[par][2][4];
        const float4 a3 = *(const float4*)&slots[par][3][0]; const float z3 = slots[par][3][4];
        u64 k0 = ((u64)__float_as_uint(a0.y) << 32) | __float_as_uint(a0.x);
        u64 k1 = ((u64)__float_as_uint(a1.y) << 32) | __float_as_uint(a1.x);
        u64 k2 = ((u64)__float_as_uint(a2.y) << 32) | __float_as_uint(a2.x);
        u64 k3 = ((u64)__float_as_uint(a3.y) << 32) | __float_as_uint(a3.x);
        u64 ka = k0; float xa = a0.z, ya = a0.w, za = z0;
        if (k1 > ka) { ka = k1; xa = a1.z; ya = a1.w; za = z1; }
        u64 kb = k2; float xb = a2.z, yb = a2.w, zb = z2;
        if (k3 > kb) { kb = k3; xb = a3.z; yb = a3.w; zb = z3; }
        if (kb > ka) { ka = kb; xa = xb; ya = yb; za = zb; }
        xl = xa; yl = ya; zl = za;
        if (t == 0) sp[s] = (int)~(u32)ka;
    }
    __syncthreads();
    for (int i = t; i < M1; i += 256) picks[b * M1 + i] = sp[i];
}

// ---------------- build combined_idx + row ----------------
__global__ __launch_bounds__(256) void build_kernel(const int* __restrict__ picks,
                                                    int* __restrict__ out) {
    int i = blockIdx.x * 256 + threadIdx.x;
    if (i < MQ) {
        int v;
        if (i < NB * M1) {
            int b = i >> 10;
            v = b * NPTS + picks[i];
        } else {
            int e = i - NB * M1;
            int b = e / M2;
            int j = e - b * M2;
            v = b * NPTS + picks[b * M1 + j];      // extra = prefix of base FPS
        }
        out[i] = v;
    }
    if (i < MQ * KK) {
        out[MQ + i] = i >> 4;                      // row = repeat(arange(MQ), 16)
    }
}

// ---------------- kNN: one wave per query ----------------
__global__ __launch_bounds__(256) void knn_kernel(const float* __restrict__ pos,
                                                  int* __restrict__ out) {
#pragma clang fp contract(off)
    const int q = blockIdx.x * 4 + (threadIdx.x >> 6);
    const int l = threadIdx.x & 63;
    if (q >= MQ) return;
    const int cidx = out[q];
    const int qb = cidx >> 12;
    const float qx = pos[(size_t)cidx * 3 + 0];
    const float qy = pos[(size_t)cidx * 3 + 1];
    const float qz = pos[(size_t)cidx * 3 + 2];
    const float* cp = pos + (size_t)qb * NPTS * 3;
    float D[64];
    float lv = __builtin_inff(); int li = 0;
#pragma unroll
    for (int j = 0; j < 64; ++j) {
        int p = j * 64 + l;
        float dx = cp[p * 3 + 0] - qx;
        float dy = cp[p * 3 + 1] - qy;
        float dz = cp[p * 3 + 2] - qz;
        float d = dx * dx + dy * dy + dz * dz;   // contract(off)
        D[j] = d;
        if (d < lv) { lv = d; li = p; }
    }
    unsigned long long mask = 0;
    int* colout = out + MQ + MQ * KK + q * KK;
    for (int r = 0; r < KK; ++r) {
        u32 klo_ = (u32)li, khi_ = __float_as_uint(lv);
        DPP_MIN(0x121); DPP_MIN(0x122); DPP_MIN(0x124); DPP_MIN(0x128);
        DPP_MIN(0x142); DPP_MIN(0x143);
        u32 bi = (u32)__builtin_amdgcn_readlane((int)klo_, 63);
        if (l == 0) colout[r] = qb * NPTS + (int)bi;
        if ((bi & 63) == (u32)l) mask |= 1ull << (bi >> 6);
        lv = __builtin_inff(); li = 0;
#pragma unroll
        for (int j = 0; j < 64; ++j) {
            bool act = ((mask >> j) & 1ull) == 0ull;
            float d = D[j];
            if (act && d < lv) { lv = d; li = j * 64 + l; }
        }
    }
}

extern "C" void kernel_launch(void* const* d_in, const int* in_sizes, int n_in,
                              void* d_out, int out_size, void* d_ws, size_t ws_size,
                              hipStream_t stream) {
    const float* pos = (const float*)d_in[0];
    int* picks = (int*)d_ws;                 // 8*1024 int32 = 32 KB
    int* out = (int*)d_out;
    fps_kernel<<<NB, 256, 0, stream>>>(pos, picks);
    build_kernel<<<(MQ * KK + 255) / 256, 256, 0, stream>>>(picks, out);
    knn_kernel<<<(MQ + 3) / 4, 256, 0, stream>>>(pos, out);
}